// Round 8
// baseline (1888.317 us; speedup 1.0000x reference)
//
#include <hip/hip_runtime.h>
#include <math.h>

#define TWO_PI 6.283185307179586f

// HARNESS MODEL (derived from rounds 0-7):
//   d_out = 33,362,176 float32 = REAL PART of reference output, [bc][l][m].
//   Writes beyond 133 MB fault (rounds 1,2,6,7); <=133 MB runs (3,4,5).
// Math:
//   xr[c][k][m] = (2pi/720) * sum_n x[c][k][n] * cos(2pi n m / 720)
//   out[c][l][m] = sum_k xr[c][k][m] * W[m][l][k]     (einsum 'bcmk,mlk->bclm', real)

// ---------------- cosine table Ec[n][m] ----------------
__global__ void build_ctab(float* __restrict__ Ec) {
    const int total = 720 * 361;
    const float sigma = TWO_PI / 720.0f;
    for (int i = blockIdx.x * blockDim.x + threadIdx.x; i < total;
         i += gridDim.x * blockDim.x) {
        int n = i / 361, m = i % 361;
        int r = (n * m) % 720;   // exact phase reduction
        float ph = (float)r * (TWO_PI / 720.0f);
        Ec[i] = sigma * cosf(ph);
    }
}

// ---------------- stage 1: xr[m][q] = sum_n A[q][n] * Ec[n][m] ----------------
// A: (Q x 720) rows of x for this chunk, q = bcl*361 + lat. grid (ceil(Q/64), 6)
__global__ __launch_bounds__(256) void s1_cos(
    const float* __restrict__ A, const float* __restrict__ Ec,
    float* __restrict__ xr, const int Q) {
    const int q0 = blockIdx.x * 64;
    const int m0 = blockIdx.y * 64;

    __shared__ __align__(16) float As[16][68];
    __shared__ __align__(16) float Bs[16][68];

    const int t = threadIdx.x;
    const int tx = t & 15, ty = t >> 4;

    float acc[4][4] = {{0.f}};

    for (int k0 = 0; k0 < 720; k0 += 16) {   // 45 exact iterations
        for (int e = t; e < 1024; e += 256) {
            int row = e >> 4, kk = e & 15;
            int q = q0 + row;
            As[kk][row] = (q < Q) ? A[(size_t)q * 720 + k0 + kk] : 0.f;
        }
        for (int e = t; e < 1024; e += 256) {
            int row = e >> 4, kk = e & 15;
            int m = m0 + row;
            Bs[kk][row] = (m < 361) ? Ec[(size_t)(k0 + kk) * 361 + m] : 0.f;
        }
        __syncthreads();
#pragma unroll
        for (int kk = 0; kk < 16; ++kk) {
            float4 a4 = *(const float4*)&As[kk][ty * 4];
            float4 b4 = *(const float4*)&Bs[kk][tx * 4];
            float aa[4] = {a4.x, a4.y, a4.z, a4.w};
            float bb[4] = {b4.x, b4.y, b4.z, b4.w};
#pragma unroll
            for (int i = 0; i < 4; ++i)
#pragma unroll
                for (int j = 0; j < 4; ++j)
                    acc[i][j] = fmaf(aa[i], bb[j], acc[i][j]);
        }
        __syncthreads();
    }

#pragma unroll
    for (int i = 0; i < 4; ++i) {
        int q = q0 + ty * 4 + i;
        if (q >= Q) continue;
#pragma unroll
        for (int j = 0; j < 4; ++j) {
            int m = m0 + tx * 4 + j;
            if (m < 361) xr[(size_t)m * Q + q] = acc[i][j];
        }
    }
}

// ---------------- stage 2: out[bc][l][m] = sum_k xr[m][bcl*361+k] * W[m][l][k] ----------------
// grid (6 l-tiles, ceil(CH/64) bc-tiles, 361 m). One f32 per (bc,l,m).
__global__ __launch_bounds__(256) void s2_real(
    const float* __restrict__ xr, const float* __restrict__ W,
    float* __restrict__ out, const int c0, const int CH) {
    const int m = blockIdx.z;
    const int bc0 = blockIdx.y * 64;
    const int l0 = blockIdx.x * 64;
    const int Q = CH * 361;

    __shared__ __align__(16) float As[16][68];
    __shared__ __align__(16) float Bs[16][68];

    const int t = threadIdx.x;
    const int tx = t & 15, ty = t >> 4;

    float acc[4][4] = {{0.f}};

    const float* Ar = xr + (size_t)m * Q;
    const float* Bm = W + (size_t)m * (361 * 361);

    for (int k0 = 0; k0 < 361; k0 += 16) {
        for (int e = t; e < 1024; e += 256) {
            int row = e >> 4, kk = e & 15;
            int kg = k0 + kk;
            int bcl = bc0 + row;
            float v = 0.f;
            if (kg < 361 && bcl < CH) v = Ar[(size_t)bcl * 361 + kg];
            As[kk][row] = v;
        }
        for (int e = t; e < 1024; e += 256) {
            int row = e >> 4, kk = e & 15;
            int l = l0 + row, kg = k0 + kk;
            float v = 0.f;
            if (l < 361 && kg < 361) v = Bm[(size_t)l * 361 + kg];
            Bs[kk][row] = v;
        }
        __syncthreads();
#pragma unroll
        for (int kk = 0; kk < 16; ++kk) {
            float4 a4 = *(const float4*)&As[kk][ty * 4];
            float4 b4 = *(const float4*)&Bs[kk][tx * 4];
            float aa[4] = {a4.x, a4.y, a4.z, a4.w};
            float bb[4] = {b4.x, b4.y, b4.z, b4.w};
#pragma unroll
            for (int i = 0; i < 4; ++i)
#pragma unroll
                for (int j = 0; j < 4; ++j)
                    acc[i][j] = fmaf(aa[i], bb[j], acc[i][j]);
        }
        __syncthreads();
    }

    // write real part: out[((c0+bcl)*361 + l)*361 + m], max index 33,362,175
#pragma unroll
    for (int i = 0; i < 4; ++i) {
        int bcl = bc0 + ty * 4 + i;
        if (bcl >= CH) continue;
        size_t bcg = (size_t)(c0 + bcl);
#pragma unroll
        for (int j = 0; j < 4; ++j) {
            int l = l0 + tx * 4 + j;
            if (l < 361)
                out[(bcg * 361 + l) * 361 + m] = acc[i][j];
        }
    }
}

extern "C" void kernel_launch(void* const* d_in, const int* in_sizes, int n_in,
                              void* d_out, int out_size, void* d_ws, size_t ws_size,
                              hipStream_t stream) {
    (void)out_size;
    // select inputs by element count: x = 66,539,520; W = 47,045,881
    const float* x = (const float*)d_in[0];
    const float* W = (const float*)d_in[1];
    if (n_in >= 2 && (in_sizes[0] == 47045881 || in_sizes[1] == 66539520)) {
        x = (const float*)d_in[1];
        W = (const float*)d_in[0];
    }
    float* ws = (float*)d_ws;
    float* out = (float*)d_out;

    const size_t offC = 0;        // Ec: 720*361 = 259,920 floats
    const size_t offX = 260096;   // plane start (16B aligned)

    // largest bc-chunk CH whose single xr plane fits ws
    const int cands[9] = {256, 128, 64, 32, 16, 8, 4, 2, 1};
    int CH = 0;
    for (int i = 0; i < 9; ++i) {
        size_t P = (size_t)361 * cands[i] * 361;
        if ((offX + P) * sizeof(float) <= ws_size) { CH = cands[i]; break; }
    }
    if (!CH) return;  // workspace too small: fail visibly, don't fault

    float* Ec = ws + offC;
    float* xr = ws + offX;

    build_ctab<<<256, 256, 0, stream>>>(Ec);

    const int Q = CH * 361;
    const int qt = (Q + 63) / 64;
    const int bct = (CH + 63) / 64;
    for (int c0 = 0; c0 < 256; c0 += CH) {
        const float* Achunk = x + (size_t)c0 * 361 * 720;
        s1_cos<<<dim3(qt, 6), 256, 0, stream>>>(Achunk, Ec, xr, Q);
        s2_real<<<dim3(6, bct, 361), 256, 0, stream>>>(xr, W, out, c0, CH);
    }
}

// Round 9
// 967.784 us; speedup vs baseline: 1.9512x; 1.9512x over previous
//
#include <hip/hip_runtime.h>
#include <math.h>

#define TWO_PI 6.283185307179586f

// HARNESS MODEL (verified R8): d_out = 33,362,176 f32 = Re(out), [bc][l][m].
// Math: xr[c][k][m] = (2pi/720) * sum_n x[c][k][n] * cos(2pi n m/720)
//       out[c][l][m] = sum_k xr[c][k][m] * W[m][l][k]
// Both GEMMs via split-bf16 MFMA (hi+lo decomposition, 3 products, f32 acc).

typedef __attribute__((ext_vector_type(8))) short bf16x8;
typedef __attribute__((ext_vector_type(4))) float f32x4;

__device__ inline unsigned short f2bf(float f) {
    union { float f; unsigned int u; } v; v.f = f;
    unsigned int u = v.u;
    return (unsigned short)((u + 0x7fffu + ((u >> 16) & 1u)) >> 16);  // RNE
}
__device__ inline float bf2f(unsigned short h) {
    union { unsigned int u; float f; } v; v.u = ((unsigned int)h) << 16;
    return v.f;
}

// ---------------- tables: EcT_hi/lo [384][736] bf16, EcT[m][n] = sigma*cos ----------------
__global__ void build_ect(unsigned short* __restrict__ Eh,
                          unsigned short* __restrict__ El) {
    const float sigma = TWO_PI / 720.0f;
    const int total = 384 * 736;
    for (int i = blockIdx.x * blockDim.x + threadIdx.x; i < total;
         i += gridDim.x * blockDim.x) {
        int m = i / 736, n = i % 736;
        float v = 0.f;
        if (m < 361 && n < 720) {
            int r = (n * m) % 720;  // exact phase reduction
            v = sigma * cosf((float)r * (TWO_PI / 720.0f));
        }
        unsigned short h = f2bf(v);
        Eh[i] = h;
        El[i] = f2bf(v - bf2f(h));
    }
}

// ---------------- stage 1: xr[m][q] = sum_n x[q][n]*EcT[m][n], split-bf16 MFMA ----------------
// grid (6 m-tiles, qt q-tiles); block 256 = 4 waves; tile 64q x 64m, K=736 (pad of 720)
__global__ __launch_bounds__(256) void s1_mfma(
    const float* __restrict__ x, const unsigned short* __restrict__ Eh,
    const unsigned short* __restrict__ El, unsigned int* __restrict__ xrp,
    const int Q) {
    __shared__ short Ah[64][40], Al[64][40], Bh[64][40], Bl[64][40];
    const int t = threadIdx.x;
    const int m0 = blockIdx.x * 64;
    const int q0 = blockIdx.y * 64;
    const int lane = t & 63, wv = t >> 6;
    const int lr = lane & 15, lk = lane >> 4;

    f32x4 acc[4];
#pragma unroll
    for (int nt = 0; nt < 4; ++nt)
#pragma unroll
        for (int r = 0; r < 4; ++r) acc[nt][r] = 0.f;

    for (int k0 = 0; k0 < 736; k0 += 32) {
        // A: 64 q-rows x 32 n, f32 -> hi/lo bf16
#pragma unroll
        for (int i = 0; i < 2; ++i) {
            int id = t + i * 256;
            int r = id >> 3, c4 = id & 7;
            int q = q0 + r, kb = k0 + c4 * 4;
            float vv[4] = {0.f, 0.f, 0.f, 0.f};
            if (q < Q) {
                if (kb + 3 < 720) {
                    float4 v4 = *(const float4*)(x + (size_t)q * 720 + kb);
                    vv[0] = v4.x; vv[1] = v4.y; vv[2] = v4.z; vv[3] = v4.w;
                } else {
#pragma unroll
                    for (int j = 0; j < 4; ++j)
                        vv[j] = (kb + j < 720) ? x[(size_t)q * 720 + kb + j] : 0.f;
                }
            }
#pragma unroll
            for (int j = 0; j < 4; ++j) {
                unsigned short h = f2bf(vv[j]);
                Ah[r][c4 * 4 + j] = (short)h;
                Al[r][c4 * 4 + j] = (short)f2bf(vv[j] - bf2f(h));
            }
        }
        // B: 64 m-rows x 32 n bf16 copy from EcT tables (uint4 = 8 bf16)
#pragma unroll
        for (int i = 0; i < 2; ++i) {
            int id = t + i * 256;
            int tab = id >> 8, rid = id & 255;
            int j = rid >> 2, s = rid & 3;
            const unsigned short* src =
                (tab ? El : Eh) + (size_t)(m0 + j) * 736 + k0 + s * 8;
            if (tab) *(uint4*)&Bl[j][s * 8] = *(const uint4*)src;
            else     *(uint4*)&Bh[j][s * 8] = *(const uint4*)src;
        }
        __syncthreads();

        bf16x8 ah = *(const bf16x8*)&Ah[wv * 16 + lr][lk * 8];
        bf16x8 al = *(const bf16x8*)&Al[wv * 16 + lr][lk * 8];
#pragma unroll
        for (int nt = 0; nt < 4; ++nt) {
            bf16x8 bh = *(const bf16x8*)&Bh[nt * 16 + lr][lk * 8];
            bf16x8 bl = *(const bf16x8*)&Bl[nt * 16 + lr][lk * 8];
            acc[nt] = __builtin_amdgcn_mfma_f32_16x16x32_bf16(ah, bh, acc[nt], 0, 0, 0);
            acc[nt] = __builtin_amdgcn_mfma_f32_16x16x32_bf16(ah, bl, acc[nt], 0, 0, 0);
            acc[nt] = __builtin_amdgcn_mfma_f32_16x16x32_bf16(al, bh, acc[nt], 0, 0, 0);
        }
        __syncthreads();
    }

    // epilogue: pack (hi,lo) into uint plane xrp[m][q]
    const int qv = q0 + wv * 16 + lk * 4;
#pragma unroll
    for (int nt = 0; nt < 4; ++nt) {
        int m = m0 + nt * 16 + lr;
        if (m >= 361) continue;
        size_t base = (size_t)m * Q;
#pragma unroll
        for (int reg = 0; reg < 4; ++reg) {
            int q = qv + reg;
            if (q < Q) {
                float v = acc[nt][reg];
                unsigned short h = f2bf(v);
                unsigned short l = f2bf(v - bf2f(h));
                xrp[base + q] = (unsigned int)h | ((unsigned int)l << 16);
            }
        }
    }
}

// ---------------- stage 2: per-m GEMM (CH bc x 361 l), split-bf16 MFMA ----------------
// grid (6 l-tiles, bc-tiles, 361 m); stg[m][bc][l] f32
__global__ __launch_bounds__(256) void s2_mfma(
    const unsigned int* __restrict__ xrp, const float* __restrict__ W,
    float* __restrict__ stg, const int CH) {
    __shared__ short Ah[64][40], Al[64][40], Bh[64][40], Bl[64][40];
    const int m = blockIdx.z;
    const int l0 = blockIdx.x * 64;
    const int bc0 = blockIdx.y * 64;
    const int Q = CH * 361;
    const int t = threadIdx.x;
    const int lane = t & 63, wv = t >> 6;
    const int lr = lane & 15, lk = lane >> 4;

    f32x4 acc[4];
#pragma unroll
    for (int nt = 0; nt < 4; ++nt)
#pragma unroll
        for (int r = 0; r < 4; ++r) acc[nt][r] = 0.f;

    if (l0 + 63 >= m) {  // lower-triangle zero-skip (verified R4/R5)
        const unsigned int* Am = xrp + (size_t)m * Q;
        const float* Wm = W + (size_t)m * 130321;
        for (int k0 = 0; k0 < 384; k0 += 32) {
            // A: 64 bc-rows x 32 k, unpack packed (hi,lo)
#pragma unroll
            for (int i = 0; i < 8; ++i) {
                int id = t + i * 256;
                int r = id >> 5, kk = id & 31;
                int bc = bc0 + r, kg = k0 + kk;
                unsigned int p = 0;
                if (bc < CH && kg < 361) p = Am[(size_t)bc * 361 + kg];
                Ah[r][kk] = (short)(p & 0xffffu);
                Al[r][kk] = (short)(p >> 16);
            }
            // B: 64 l-rows x 32 k from W, f32 -> hi/lo
#pragma unroll
            for (int i = 0; i < 8; ++i) {
                int id = t + i * 256;
                int r = id >> 5, kk = id & 31;
                int l = l0 + r, kg = k0 + kk;
                float v = 0.f;
                if (l < 361 && kg < 361) v = Wm[(size_t)l * 361 + kg];
                unsigned short h = f2bf(v);
                Bh[r][kk] = (short)h;
                Bl[r][kk] = (short)f2bf(v - bf2f(h));
            }
            __syncthreads();

            bf16x8 ah = *(const bf16x8*)&Ah[wv * 16 + lr][lk * 8];
            bf16x8 al = *(const bf16x8*)&Al[wv * 16 + lr][lk * 8];
#pragma unroll
            for (int nt = 0; nt < 4; ++nt) {
                bf16x8 bh = *(const bf16x8*)&Bh[nt * 16 + lr][lk * 8];
                bf16x8 bl = *(const bf16x8*)&Bl[nt * 16 + lr][lk * 8];
                acc[nt] = __builtin_amdgcn_mfma_f32_16x16x32_bf16(ah, bh, acc[nt], 0, 0, 0);
                acc[nt] = __builtin_amdgcn_mfma_f32_16x16x32_bf16(ah, bl, acc[nt], 0, 0, 0);
                acc[nt] = __builtin_amdgcn_mfma_f32_16x16x32_bf16(al, bh, acc[nt], 0, 0, 0);
            }
            __syncthreads();
        }
    }

    // epilogue: stg[(m*CH + bc)*361 + l]
    const int bcv = bc0 + wv * 16 + lk * 4;
#pragma unroll
    for (int nt = 0; nt < 4; ++nt) {
        int l = l0 + nt * 16 + lr;
        if (l >= 361) continue;
#pragma unroll
        for (int reg = 0; reg < 4; ++reg) {
            int bc = bcv + reg;
            if (bc < CH)
                stg[((size_t)m * CH + bc) * 361 + l] = acc[nt][reg];
        }
    }
}

// ---------------- transpose stg [m][q'] -> out [c0*361+q'][m] ----------------
__global__ __launch_bounds__(256) void transpose_out(const float* __restrict__ stg,
                                                     float* __restrict__ out,
                                                     const int c0, const int CH) {
    __shared__ float tile[32][33];
    const int Q = CH * 361;
    const int m0 = blockIdx.y * 32, q0 = blockIdx.x * 32;
    const int tx = threadIdx.x & 31, ty = threadIdx.x >> 5;
    for (int i = ty; i < 32; i += 8) {
        int mm = m0 + i, q = q0 + tx;
        if (mm < 361 && q < Q) tile[i][tx] = stg[(size_t)mm * Q + q];
    }
    __syncthreads();
    for (int i = ty; i < 32; i += 8) {
        int q = q0 + i, mm = m0 + tx;
        if (mm < 361 && q < Q)
            out[((size_t)c0 * 361 + q) * 361 + mm] = tile[tx][i];
    }
}

extern "C" void kernel_launch(void* const* d_in, const int* in_sizes, int n_in,
                              void* d_out, int out_size, void* d_ws, size_t ws_size,
                              hipStream_t stream) {
    (void)out_size;
    // select inputs by element count: x = 66,539,520; W = 47,045,881
    const float* x = (const float*)d_in[0];
    const float* W = (const float*)d_in[1];
    if (n_in >= 2 && (in_sizes[0] == 47045881 || in_sizes[1] == 66539520)) {
        x = (const float*)d_in[1];
        W = (const float*)d_in[0];
    }
    float* out = (float*)d_out;

    // ws layout (bytes): EcT_hi | EcT_lo | xrp (uint, CH*130321) | stg (f32, CH*130321)
    const size_t offEh = 0;
    const size_t offEl = 565248;                 // 384*736*2
    const size_t offData = 1130496;

    const int cands[6] = {256, 128, 64, 32, 16, 8};
    int CH = 0;
    for (int i = 0; i < 6; ++i) {
        size_t need = offData + 2ull * cands[i] * 130321ull * 4ull;
        if (need <= ws_size) { CH = cands[i]; break; }
    }
    if (!CH) return;  // workspace too small: fail visibly, don't fault

    unsigned short* Eh = (unsigned short*)((char*)d_ws + offEh);
    unsigned short* El = (unsigned short*)((char*)d_ws + offEl);
    unsigned int* xrp = (unsigned int*)((char*)d_ws + offData);
    float* stg = (float*)((char*)d_ws + offData + (size_t)CH * 130321ull * 4ull);

    build_ect<<<256, 256, 0, stream>>>(Eh, El);

    const int Q = CH * 361;
    const int qt = (Q + 63) / 64;
    const int bct = (CH + 63) / 64;
    for (int c0 = 0; c0 < 256; c0 += CH) {
        s1_mfma<<<dim3(6, qt), 256, 0, stream>>>(
            x + (size_t)c0 * 361 * 720, Eh, El, xrp, Q);
        s2_mfma<<<dim3(6, bct, 361), 256, 0, stream>>>(xrp, W, stg, CH);
        transpose_out<<<dim3((Q + 31) / 32, 12), 256, 0, stream>>>(stg, out, c0, CH);
    }
}

// Round 10
// 824.693 us; speedup vs baseline: 2.2897x; 1.1735x over previous
//
#include <hip/hip_runtime.h>
#include <math.h>

#define TWO_PI 6.283185307179586f

// HARNESS MODEL (verified R8/R9): d_out = 33,362,176 f32 = Re(out), [bc][l][m].
// Math: xr[c][k][m] = (2pi/720) * sum_n x[c][k][n] * cos(2pi n m/720)
//       out[c][l][m] = sum_k xr[c][k][m] * W[m][l][k]
// Split-bf16 MFMA (hi+lo, 3 products, f32 acc) for both GEMMs.

typedef __attribute__((ext_vector_type(8))) short bf16x8;
typedef __attribute__((ext_vector_type(4))) float f32x4;

__device__ inline unsigned short f2bf(float f) {
    union { float f; unsigned int u; } v; v.f = f;
    unsigned int u = v.u;
    return (unsigned short)((u + 0x7fffu + ((u >> 16) & 1u)) >> 16);  // RNE
}
__device__ inline float bf2f(unsigned short h) {
    union { unsigned int u; float f; } v; v.u = ((unsigned int)h) << 16;
    return v.f;
}
__device__ inline unsigned int packhl(float v) {
    unsigned short h = f2bf(v);
    unsigned short l = f2bf(v - bf2f(h));
    return (unsigned int)h | ((unsigned int)l << 16);
}
__device__ inline void split2(float a, float b, unsigned int& hh, unsigned int& ll) {
    unsigned short ha = f2bf(a), hb = f2bf(b);
    unsigned short la = f2bf(a - bf2f(ha)), lb = f2bf(b - bf2f(hb));
    hh = (unsigned int)ha | ((unsigned int)hb << 16);
    ll = (unsigned int)la | ((unsigned int)lb << 16);
}
// bijective chunked XCD swizzle (m204): consecutive work-ids land on one XCD
__device__ inline int xcd_work(int bid, int nwg) {
    int q = nwg >> 3, r = nwg & 7;
    int xcd = bid & 7, ord = bid >> 3;
    return (xcd < r ? xcd * (q + 1) : r * (q + 1) + (xcd - r) * q) + ord;
}

// ---------------- tables: EcT_hi/lo [384][736] bf16, EcT[m][n] = sigma*cos ----------------
__global__ void build_ect(unsigned short* __restrict__ Eh,
                          unsigned short* __restrict__ El) {
    const float sigma = TWO_PI / 720.0f;
    const int total = 384 * 736;
    for (int i = blockIdx.x * blockDim.x + threadIdx.x; i < total;
         i += gridDim.x * blockDim.x) {
        int m = i / 736, n = i % 736;
        float v = 0.f;
        if (m < 361 && n < 720) {
            int r = (n * m) % 720;  // exact phase reduction
            v = sigma * cosf((float)r * (TWO_PI / 720.0f));
        }
        unsigned short h = f2bf(v);
        Eh[i] = h;
        El[i] = f2bf(v - bf2f(h));
    }
}

// ---------------- stage 1: xr[m][q] = sum_n x[q][n]*EcT[m][n] ----------------
// block 512 thr = 8 waves; tile 64q x 192m; grid = qt*2 (flattened, swizzled)
__global__ __launch_bounds__(512, 4) void s1_mfma(
    const float* __restrict__ x, const unsigned short* __restrict__ Eh,
    const unsigned short* __restrict__ El, unsigned int* __restrict__ xrp,
    const int Q) {
    __shared__ short Ah[64][40], Al[64][40];     // 5 KB each
    __shared__ short Bh[192][40], Bl[192][40];   // 15 KB each -> 40 KB

    const int work = xcd_work(blockIdx.x, gridDim.x);
    const int q0 = (work >> 1) * 64;
    const int m0g = (work & 1) * 192;
    const int t = threadIdx.x;
    const int lane = t & 63, wv = t >> 6;
    const int lr = lane & 15, lk = lane >> 4;
    const int wq = wv & 3, wm = wv >> 2;   // 4 q-subtiles x 2 m-subtiles

    f32x4 acc[6];
#pragma unroll
    for (int nj = 0; nj < 6; ++nj)
#pragma unroll
        for (int r = 0; r < 4; ++r) acc[nj][r] = 0.f;

    for (int k0 = 0; k0 < 736; k0 += 32) {
        // A: 64 rows x 16 f32-pairs -> hi/lo packed 4B LDS stores
#pragma unroll
        for (int i = 0; i < 2; ++i) {
            int id = t + i * 512;
            int r = id >> 4, kp = id & 15;
            int q = q0 + r, kg = k0 + kp * 2;
            float va = 0.f, vb = 0.f;
            if (q < Q) {
                if (kg + 1 < 720) {
                    float2 v2 = *(const float2*)(x + (size_t)q * 720 + kg);
                    va = v2.x; vb = v2.y;
                } else if (kg < 720) {
                    va = x[(size_t)q * 720 + kg];
                }
            }
            unsigned int hh, ll;
            split2(va, vb, hh, ll);
            *(unsigned int*)&Ah[r][kp * 2] = hh;
            *(unsigned int*)&Al[r][kp * 2] = ll;
        }
        // B: 192 rows x 32k bf16 copies from tables (uint4 = 8 bf16)
#pragma unroll
        for (int i = 0; i < 3; ++i) {
            int id = t + i * 512;          // 0..1535
            int tab = id / 768, rid = id % 768;
            int r = rid >> 2, s = rid & 3;
            const unsigned short* src =
                (tab ? El : Eh) + (size_t)(m0g + r) * 736 + k0 + s * 8;
            uint4 v = *(const uint4*)src;
            if (tab) *(uint4*)&Bl[r][s * 8] = v;
            else     *(uint4*)&Bh[r][s * 8] = v;
        }
        __syncthreads();

        bf16x8 ah = *(const bf16x8*)&Ah[wq * 16 + lr][lk * 8];
        bf16x8 al = *(const bf16x8*)&Al[wq * 16 + lr][lk * 8];
#pragma unroll
        for (int nj = 0; nj < 6; ++nj) {
            bf16x8 bh = *(const bf16x8*)&Bh[wm * 96 + nj * 16 + lr][lk * 8];
            bf16x8 bl = *(const bf16x8*)&Bl[wm * 96 + nj * 16 + lr][lk * 8];
            acc[nj] = __builtin_amdgcn_mfma_f32_16x16x32_bf16(ah, bh, acc[nj], 0, 0, 0);
            acc[nj] = __builtin_amdgcn_mfma_f32_16x16x32_bf16(ah, bl, acc[nj], 0, 0, 0);
            acc[nj] = __builtin_amdgcn_mfma_f32_16x16x32_bf16(al, bh, acc[nj], 0, 0, 0);
        }
        __syncthreads();
    }

    // epilogue: D col(lane&15)=m, row(lk*4+reg)=q  (R9-verified mapping)
#pragma unroll
    for (int nj = 0; nj < 6; ++nj) {
        int m = m0g + wm * 96 + nj * 16 + lr;
        if (m >= 361) continue;
        size_t base = (size_t)m * Q;
#pragma unroll
        for (int reg = 0; reg < 4; ++reg) {
            int q = q0 + wq * 16 + lk * 4 + reg;
            if (q < Q) xrp[base + q] = packhl(acc[nj][reg]);
        }
    }
}

// ---------------- stage 2: per-m GEMM, tile 256bc x 64l ----------------
// block 512 thr = 8 waves (4 bc-sub x 2 l-sub); grid = 361*6 flattened+swizzled
__global__ __launch_bounds__(512, 4) void s2_mfma(
    const unsigned int* __restrict__ xrp, const float* __restrict__ W,
    float* __restrict__ stg, const int CH) {
    __shared__ short Ah[256][40], Al[256][40];   // 20 KB each
    __shared__ short Bh[64][40], Bl[64][40];     // 5 KB each -> 50 KB

    const int work = xcd_work(blockIdx.x, gridDim.x);
    const int m = work / 6, lt = work % 6;
    const int l0 = lt * 64;
    const int Q = CH * 361;
    const int t = threadIdx.x;
    const int lane = t & 63, wv = t >> 6;
    const int lr = lane & 15, lk = lane >> 4;
    const int wbc = wv >> 1, wl = wv & 1;

    f32x4 acc[4][2];
#pragma unroll
    for (int fi = 0; fi < 4; ++fi)
#pragma unroll
        for (int ni = 0; ni < 2; ++ni)
#pragma unroll
            for (int r = 0; r < 4; ++r) acc[fi][ni][r] = 0.f;

    if (l0 + 63 >= m) {  // lower-triangle zero-skip (verified R4/R5)
        const unsigned int* Am = xrp + (size_t)m * Q;
        const float* Wm = W + (size_t)m * 130321;
        for (int k0 = 0; k0 < 384; k0 += 32) {
            // A: 256 rows x 16 packed-pairs (unpack hi/lo)
#pragma unroll
            for (int i = 0; i < 8; ++i) {
                int id = t + i * 512;
                int r = id >> 4, kp = id & 15;
                int kg = k0 + kp * 2;
                unsigned int p0 = 0, p1 = 0;
                if (r < CH) {
                    size_t base = (size_t)r * 361;
                    if (kg < 361) p0 = Am[base + kg];
                    if (kg + 1 < 361) p1 = Am[base + kg + 1];
                }
                *(unsigned int*)&Ah[r][kp * 2] = (p0 & 0xffffu) | (p1 << 16);
                *(unsigned int*)&Al[r][kp * 2] = (p0 >> 16) | (p1 & 0xffff0000u);
            }
            // B: 64 rows x 16 f32-pairs from W -> hi/lo
#pragma unroll
            for (int i = 0; i < 2; ++i) {
                int id = t + i * 512;
                int r = id >> 4, kp = id & 15;
                int l = l0 + r, kg = k0 + kp * 2;
                float va = 0.f, vb = 0.f;
                if (l < 361) {
                    size_t base = (size_t)l * 361;
                    if (kg < 361) va = Wm[base + kg];
                    if (kg + 1 < 361) vb = Wm[base + kg + 1];
                }
                unsigned int hh, ll;
                split2(va, vb, hh, ll);
                *(unsigned int*)&Bh[r][kp * 2] = hh;
                *(unsigned int*)&Bl[r][kp * 2] = ll;
            }
            __syncthreads();
#pragma unroll
            for (int fi = 0; fi < 4; ++fi) {
                bf16x8 ah = *(const bf16x8*)&Ah[wbc * 64 + fi * 16 + lr][lk * 8];
                bf16x8 al = *(const bf16x8*)&Al[wbc * 64 + fi * 16 + lr][lk * 8];
#pragma unroll
                for (int ni = 0; ni < 2; ++ni) {
                    bf16x8 bh = *(const bf16x8*)&Bh[wl * 32 + ni * 16 + lr][lk * 8];
                    bf16x8 bl = *(const bf16x8*)&Bl[wl * 32 + ni * 16 + lr][lk * 8];
                    acc[fi][ni] = __builtin_amdgcn_mfma_f32_16x16x32_bf16(ah, bh, acc[fi][ni], 0, 0, 0);
                    acc[fi][ni] = __builtin_amdgcn_mfma_f32_16x16x32_bf16(ah, bl, acc[fi][ni], 0, 0, 0);
                    acc[fi][ni] = __builtin_amdgcn_mfma_f32_16x16x32_bf16(al, bh, acc[fi][ni], 0, 0, 0);
                }
            }
            __syncthreads();
        }
    }

    // epilogue (all blocks write, incl. skipped zeros): stg[(m*CH+bc)*361+l]
#pragma unroll
    for (int fi = 0; fi < 4; ++fi) {
#pragma unroll
        for (int ni = 0; ni < 2; ++ni) {
            int l = l0 + wl * 32 + ni * 16 + lr;
#pragma unroll
            for (int reg = 0; reg < 4; ++reg) {
                int bc = wbc * 64 + fi * 16 + lk * 4 + reg;
                if (bc < CH && l < 361)
                    stg[((size_t)m * CH + bc) * 361 + l] = acc[fi][ni][reg];
            }
        }
    }
}

// ---------------- transpose stg [m][q'] -> out [c0*361+q'][m] ----------------
__global__ __launch_bounds__(256) void transpose_out(const float* __restrict__ stg,
                                                     float* __restrict__ out,
                                                     const int c0, const int CH) {
    __shared__ float tile[32][33];
    const int Q = CH * 361;
    const int m0 = blockIdx.y * 32, q0 = blockIdx.x * 32;
    const int tx = threadIdx.x & 31, ty = threadIdx.x >> 5;
    for (int i = ty; i < 32; i += 8) {
        int mm = m0 + i, q = q0 + tx;
        if (mm < 361 && q < Q) tile[i][tx] = stg[(size_t)mm * Q + q];
    }
    __syncthreads();
    for (int i = ty; i < 32; i += 8) {
        int q = q0 + i, mm = m0 + tx;
        if (mm < 361 && q < Q)
            out[((size_t)c0 * 361 + q) * 361 + mm] = tile[tx][i];
    }
}

extern "C" void kernel_launch(void* const* d_in, const int* in_sizes, int n_in,
                              void* d_out, int out_size, void* d_ws, size_t ws_size,
                              hipStream_t stream) {
    (void)out_size;
    // select inputs by element count: x = 66,539,520; W = 47,045,881
    const float* x = (const float*)d_in[0];
    const float* W = (const float*)d_in[1];
    if (n_in >= 2 && (in_sizes[0] == 47045881 || in_sizes[1] == 66539520)) {
        x = (const float*)d_in[1];
        W = (const float*)d_in[0];
    }
    float* out = (float*)d_out;

    // ws layout (bytes): EcT_hi | EcT_lo | xrp (uint, CH*130321) | stg (f32, CH*130321)
    const size_t offEh = 0;
    const size_t offEl = 565248;                 // 384*736*2
    const size_t offData = 1130496;

    const int cands[6] = {256, 128, 64, 32, 16, 8};
    int CH = 0;
    for (int i = 0; i < 6; ++i) {
        size_t need = offData + 2ull * cands[i] * 130321ull * 4ull;
        if (need <= ws_size) { CH = cands[i]; break; }
    }
    if (!CH) return;  // workspace too small: fail visibly, don't fault

    unsigned short* Eh = (unsigned short*)((char*)d_ws + offEh);
    unsigned short* El = (unsigned short*)((char*)d_ws + offEl);
    unsigned int* xrp = (unsigned int*)((char*)d_ws + offData);
    float* stg = (float*)((char*)d_ws + offData + (size_t)CH * 130321ull * 4ull);

    build_ect<<<256, 256, 0, stream>>>(Eh, El);

    const int Q = CH * 361;
    const int qt = (Q + 63) / 64;
    for (int c0 = 0; c0 < 256; c0 += CH) {
        s1_mfma<<<qt * 2, 512, 0, stream>>>(
            x + (size_t)c0 * 361 * 720, Eh, El, xrp, Q);
        s2_mfma<<<361 * 6, 512, 0, stream>>>(xrp, W, stg, CH);
        transpose_out<<<dim3((Q + 31) / 32, 12), 256, 0, stream>>>(stg, out, c0, CH);
    }
}